// Round 4
// baseline (127.384 us; speedup 1.0000x reference)
//
#include <hip/hip_runtime.h>

#define BB 256
#define SS 512
#define DD 64
#define LN_EPS 1e-5f

typedef float v2f __attribute__((ext_vector_type(2)));

// Degree-4 minimax (Chebyshev-derived) poly for e^z on [-2, 0].
// Max abs err ~3e-4; P(z) >= 0.135 on the interval (no sign flip).
#define PD4 0.0161103f
#define PD3 0.1296878f
#define PD2 0.4760500f
#define PD1 0.9943640f
#define PD0 0.9997979f

// One fused kernel: 768 blocks (B x 3 tasks) x 512 threads.
// Algebra: h = x*pw + pb (rank-1+const) propagates to
//   attn[q,k] = softmax_k((alpha*x_q + gamma)*y_k)
//   row result r_q = x_q*pw + t_q*u + e,  t_q = sum_k attn*y_k (scalar!)
//   LN closed-form via 3x3 Gram of centered {pw,u,e}; seq-mean needs only
//   P=mean(x*inv), T=mean(t*inv), I=mean(inv).
// exp via full-rate packed poly (args provably in [-1.3,0], clamped at -2).
__global__ __launch_bounds__(512, 6) void fused_kernel(
    const float* __restrict__ x_src, const float* __restrict__ x_tgt,
    const float* __restrict__ proj_w, const float* __restrict__ proj_b,
    const float* __restrict__ sa_in_w, const float* __restrict__ sa_in_b,
    const float* __restrict__ sa_out_w, const float* __restrict__ sa_out_b,
    const float* __restrict__ sa_ln_g, const float* __restrict__ sa_ln_b,
    const float* __restrict__ ca_in_w, const float* __restrict__ ca_in_b,
    const float* __restrict__ ca_out_w, const float* __restrict__ ca_out_b,
    const float* __restrict__ ca_ln_g, const float* __restrict__ ca_ln_b,
    float* __restrict__ out)
{
    const int tid  = threadIdx.x;
    const int b    = blockIdx.x / 3;
    const int task = blockIdx.x % 3;
    // task 0: sa_src (x=xs,y=xs) -> z_src_private @ B*D
    // task 1: sa_tgt (x=xt,y=xt) -> z_tgt_private @ 2*B*D
    // task 2: ca     (x=xs,y=xt) -> z_shared      @ 0
    const float* xq_g = (task == 1) ? (x_tgt + b * SS) : (x_src + b * SS);
    const float* y_g  = (task == 0) ? (x_src + b * SS) : (x_tgt + b * SS);
    const int type    = (task == 2) ? 1 : 0;
    const float* in_w  = type ? ca_in_w  : sa_in_w;
    const float* in_b  = type ? ca_in_b  : sa_in_b;
    const float* out_w = type ? ca_out_w : sa_out_w;
    const float* out_b = type ? ca_out_b : sa_out_b;
    const float* g     = type ? ca_ln_g  : sa_ln_g;
    const float* lb    = type ? ca_ln_b  : sa_ln_b;
    const int out_base = ((task == 0) ? BB * DD : (task == 1) ? 2 * BB * DD : 0) + b * DD;

    __shared__ float sv[6][DD];        // aq,ak,av,cq,ck,cv
    __shared__ float cvec[3][DD];      // centered pw / u / e  (stage2 parks u,e here)
    __shared__ float cst[8];           // alpha,gamma,G11..G23
    __shared__ __align__(16) float ys_l[SS];
    __shared__ float rmax[8], rmin[8], rP[8], rT[8], rI[8];
    __shared__ float bc[5];            // ymax,ymin,P,T,I

    const int wave = tid >> 6, lane = tid & 63;

    // main-phase global loads issued early
    const float xq = xq_g[tid];
    const float y  = y_g[tid];
    ys_l[tid] = y;

    // per-wave y max/min (for the softmax shift)
    {
        float mx = y, mn = y;
        #pragma unroll
        for (int o = 32; o > 0; o >>= 1) {
            mx = fmaxf(mx, __shfl_down(mx, o));
            mn = fminf(mn, __shfl_down(mn, o));
        }
        if (lane == 0) { rmax[wave] = mx; rmin[wave] = mn; }
    }

    // ---- prep stage 1: 6 matvecs {q,k,v} x {pw,pb} (384 threads) ----
    if (tid < 384) {
        const int mat = tid >> 6, d = tid & 63;
        const int rb = mat % 3, vecsel = mat / 3;
        const float* W = in_w + (rb * DD + d) * DD;
        const float* v = vecsel ? proj_b : proj_w;
        float s = 0.f;
        #pragma unroll
        for (int e = 0; e < DD; e += 4) {
            float4 wv = *(const float4*)(W + e);
            float4 vv = *(const float4*)(v + e);
            s += wv.x * vv.x + wv.y * vv.y + wv.z * vv.z + wv.w * vv.w;
        }
        if (vecsel) s += in_b[rb * DD + d];
        sv[mat][d] = s;
    }
    __syncthreads();

    // ---- stage 2: u = Wo@av ; e = pb + Wo@cv + bo (128 threads) ----
    if (tid < 128) {
        const int which = tid >> 6, d = tid & 63;
        const float* W = out_w + d * DD;
        const float* v = sv[which ? 5 : 2];   // cv : av
        float s = 0.f;
        #pragma unroll
        for (int e = 0; e < DD; e += 4) {
            float4 wv = *(const float4*)(W + e);
            s += wv.x * v[e] + wv.y * v[e + 1] + wv.z * v[e + 2] + wv.w * v[e + 3];
        }
        if (which) cvec[2][d] = proj_b[d] + s + out_b[d];  // e (uncentered)
        else       cvec[1][d] = s;                          // u (uncentered)
    }
    // block-combine y max/min (last thread, parallel with stage 2)
    if (tid == 511) {
        float a = rmax[0], m = rmin[0];
        #pragma unroll
        for (int i = 1; i < 8; ++i) { a = fmaxf(a, rmax[i]); m = fminf(m, rmin[i]); }
        bc[0] = a; bc[1] = m;
    }
    __syncthreads();

    // ---- stage 3: scalars + Gram + centering (wave 0) ----
    if (wave == 0) {
        auto wred = [](float x) {
            #pragma unroll
            for (int o = 32; o > 0; o >>= 1) x += __shfl_down(x, o);
            return __shfl(x, 0);
        };
        const float aq = sv[0][lane], ak = sv[1][lane], cq = sv[3][lane];
        const float pw = proj_w[lane];
        const float u  = cvec[1][lane], e = cvec[2][lane];

        const float alpha = wred(aq * ak) * 0.125f;   // /sqrt(64)
        const float gamma = wred(cq * ak) * 0.125f;
        const float m_pw = wred(pw) * (1.f / DD);
        const float m_u  = wred(u)  * (1.f / DD);
        const float m_e  = wred(e)  * (1.f / DD);
        const float a  = pw - m_pw;
        const float bb = u  - m_u;
        const float c  = e  - m_e;
        const float G11 = wred(a * a)   * (1.f / DD);
        const float G22 = wred(bb * bb) * (1.f / DD);
        const float G33 = wred(c * c)   * (1.f / DD);
        const float G12 = wred(a * bb)  * (1.f / DD);
        const float G13 = wred(a * c)   * (1.f / DD);
        const float G23 = wred(bb * c)  * (1.f / DD);

        cvec[0][lane] = a; cvec[1][lane] = bb; cvec[2][lane] = c;
        if (lane == 0) {
            cst[0] = alpha; cst[1] = gamma;
            cst[2] = G11; cst[3] = G22; cst[4] = G33;
            cst[5] = G12; cst[6] = G13; cst[7] = G23;
        }
    }
    __syncthreads();

    const float ymax = bc[0], ymin = bc[1];
    const float alpha = cst[0], gamma = cst[1];
    const float G11 = cst[2], G22 = cst[3], G33 = cst[4];
    const float G12 = cst[5], G13 = cst[6], G23 = cst[7];

    const float c   = alpha * xq + gamma;
    const float nml = -fmaxf(c * ymax, c * ymin);   // arg = c*y + nml <= 0
    const v2f cl2 = { c, c };
    const v2f nm2 = { nml, nml };
    const v2f m2  = { -2.f, -2.f };
    const v2f pd4 = { PD4, PD4 }, pd3 = { PD3, PD3 }, pd2 = { PD2, PD2 };
    const v2f pd1 = { PD1, PD1 }, pd0 = { PD0, PD0 };

    v2f den0 = {0.f,0.f}, den1 = {0.f,0.f}, den2 = {0.f,0.f}, den3 = {0.f,0.f};
    v2f num0 = {0.f,0.f}, num1 = {0.f,0.f}, num2 = {0.f,0.f}, num3 = {0.f,0.f};

    auto step = [&](float4 yv, v2f& den, v2f& num) {
        v2f y01 = { yv.x, yv.y }, y23 = { yv.z, yv.w };
        v2f z0 = __builtin_elementwise_max(cl2 * y01 + nm2, m2);
        v2f z1 = __builtin_elementwise_max(cl2 * y23 + nm2, m2);
        v2f E0 = (((pd4 * z0 + pd3) * z0 + pd2) * z0 + pd1) * z0 + pd0;
        v2f E1 = (((pd4 * z1 + pd3) * z1 + pd2) * z1 + pd1) * z1 + pd0;
        den += E0; num += y01 * E0;
        den += E1; num += y23 * E1;
    };

    #pragma unroll 2
    for (int k = 0; k < SS; k += 16) {
        float4 ya = *(const float4*)&ys_l[k];
        float4 yb = *(const float4*)&ys_l[k + 4];
        float4 yc = *(const float4*)&ys_l[k + 8];
        float4 yd = *(const float4*)&ys_l[k + 12];
        step(ya, den0, num0);
        step(yb, den1, num1);
        step(yc, den2, num2);
        step(yd, den3, num3);
    }
    v2f denv = (den0 + den1) + (den2 + den3);
    v2f numv = (num0 + num1) + (num2 + num3);
    const float t = (numv.x + numv.y) / (denv.x + denv.y);

    const float var = xq * xq * G11 + t * t * G22 + G33
                    + 2.f * (xq * t * G12 + xq * G13 + t * G23);
    const float inv = rsqrtf(var + LN_EPS);

    float pP = xq * inv, pT = t * inv, pI = inv;
    #pragma unroll
    for (int o = 32; o > 0; o >>= 1) {
        pP += __shfl_down(pP, o);
        pT += __shfl_down(pT, o);
        pI += __shfl_down(pI, o);
    }
    if (lane == 0) { rP[wave] = pP; rT[wave] = pT; rI[wave] = pI; }
    __syncthreads();
    if (tid == 0) {
        float sP = 0.f, sT = 0.f, sI = 0.f;
        #pragma unroll
        for (int i = 0; i < 8; ++i) { sP += rP[i]; sT += rT[i]; sI += rI[i]; }
        bc[2] = sP * (1.f / SS); bc[3] = sT * (1.f / SS); bc[4] = sI * (1.f / SS);
    }
    __syncthreads();

    if (tid < DD) {
        const float P = bc[2], T = bc[3], I = bc[4];
        float z = (P * cvec[0][tid] + T * cvec[1][tid] + I * cvec[2][tid]) * g[tid] + lb[tid];
        out[out_base + tid] = z;
    }
}

extern "C" void kernel_launch(void* const* d_in, const int* in_sizes, int n_in,
                              void* d_out, int out_size, void* d_ws, size_t ws_size,
                              hipStream_t stream) {
    const float* x_src    = (const float*)d_in[0];
    const float* x_tgt    = (const float*)d_in[1];
    const float* proj_w   = (const float*)d_in[2];
    const float* proj_b   = (const float*)d_in[3];
    const float* sa_in_w  = (const float*)d_in[4];
    const float* sa_in_b  = (const float*)d_in[5];
    const float* sa_out_w = (const float*)d_in[6];
    const float* sa_out_b = (const float*)d_in[7];
    const float* sa_ln_g  = (const float*)d_in[8];
    const float* sa_ln_b  = (const float*)d_in[9];
    const float* ca_in_w  = (const float*)d_in[10];
    const float* ca_in_b  = (const float*)d_in[11];
    const float* ca_out_w = (const float*)d_in[12];
    const float* ca_out_b = (const float*)d_in[13];
    const float* ca_ln_g  = (const float*)d_in[14];
    const float* ca_ln_b  = (const float*)d_in[15];
    float* out = (float*)d_out;

    fused_kernel<<<BB * 3, 512, 0, stream>>>(
        x_src, x_tgt, proj_w, proj_b,
        sa_in_w, sa_in_b, sa_out_w, sa_out_b, sa_ln_g, sa_ln_b,
        ca_in_w, ca_in_b, ca_out_w, ca_out_b, ca_ln_g, ca_ln_b,
        out);
}

// Round 5
// 105.690 us; speedup vs baseline: 1.2053x; 1.2053x over previous
//
#include <hip/hip_runtime.h>

#define BB 256
#define SS 512
#define DD 64
#define LN_EPS 1e-5f
#define L2E 1.4426950408889634f
#define NN 16            // Chebyshev nodes
#define PI_F 3.14159265358979f

__device__ __forceinline__ float fexp2(float x) {
#if __has_builtin(__builtin_amdgcn_exp2f)
    return __builtin_amdgcn_exp2f(x);
#else
    float r; asm("v_exp_f32 %0, %1" : "=v"(r) : "v"(x)); return r;
#endif
}

// 768 blocks (B x 3 tasks) x 512 threads.
// Algebra: h = x*pw + pb (rank-1+const) =>
//   attn[q,k] = softmax_k(c_q * y_k),  c_q = alpha*x_q + gamma
//   r_q = x_q*pw + t_q*u + e,  t_q = sum_k attn*y_k  (a SCALAR per row)
//   t_q = f'(c)/f(c), f(c)=sum_k e^{c y_k} — smooth in the scalar c.
// Instead of 512 exps/query: evaluate t at 16 Chebyshev nodes of the block's
// actual c-range (exact exp), DCT -> coefficients, per-query Clenshaw.
// LN closed-form via 3x3 Gram of centered {pw,u,e}; seq-mean needs only
// P=mean(x*inv), T=mean(t*inv), I=mean(inv).
__global__ __launch_bounds__(512) void fused_kernel(
    const float* __restrict__ x_src, const float* __restrict__ x_tgt,
    const float* __restrict__ proj_w, const float* __restrict__ proj_b,
    const float* __restrict__ sa_in_w, const float* __restrict__ sa_in_b,
    const float* __restrict__ sa_out_w, const float* __restrict__ sa_out_b,
    const float* __restrict__ sa_ln_g, const float* __restrict__ sa_ln_b,
    const float* __restrict__ ca_in_w, const float* __restrict__ ca_in_b,
    const float* __restrict__ ca_out_w, const float* __restrict__ ca_out_b,
    const float* __restrict__ ca_ln_g, const float* __restrict__ ca_ln_b,
    float* __restrict__ out)
{
    const int tid  = threadIdx.x;
    const int b    = blockIdx.x / 3;
    const int task = blockIdx.x % 3;
    // task 0: sa_src (x=xs,y=xs) -> z_src_private @ B*D
    // task 1: sa_tgt (x=xt,y=xt) -> z_tgt_private @ 2*B*D
    // task 2: ca     (x=xs,y=xt) -> z_shared      @ 0
    const float* xq_g = (task == 1) ? (x_tgt + b * SS) : (x_src + b * SS);
    const float* y_g  = (task == 0) ? (x_src + b * SS) : (x_tgt + b * SS);
    const int type    = (task == 2) ? 1 : 0;
    const float* in_w  = type ? ca_in_w  : sa_in_w;
    const float* in_b  = type ? ca_in_b  : sa_in_b;
    const float* out_w = type ? ca_out_w : sa_out_w;
    const float* out_b = type ? ca_out_b : sa_out_b;
    const float* g     = type ? ca_ln_g  : sa_ln_g;
    const float* lb    = type ? ca_ln_b  : sa_ln_b;
    const int out_base = ((task == 0) ? BB * DD : (task == 1) ? 2 * BB * DD : 0) + b * DD;

    __shared__ float sv[6][DD];        // aq,ak,av,cq,ck,cv
    __shared__ float cvec[3][DD];      // centered pw/u/e (stage2 parks u,e in [1],[2])
    __shared__ float cst[8];           // alpha,gamma,G11,G22,G33,G12,G13,G23
    __shared__ __align__(16) float ys_l[SS];
    __shared__ float rymx[8], rymn[8], rxmx[8], rxmn[8];
    __shared__ float rP[8], rT[8], rI[8];
    __shared__ float tj_l[NN];
    __shared__ __align__(16) float ac_l[NN];
    __shared__ float bc[7];            // ymax,ymin,xmax,xmin,P,T,I

    const int wave = tid >> 6, lane = tid & 63;

    // ---- phase A: loads + per-wave min/max of x and y ----
    const float xq = xq_g[tid];
    const float y  = y_g[tid];
    ys_l[tid] = y;
    {
        float ymx = y, ymn = y, xmx = xq, xmn = xq;
        #pragma unroll
        for (int o = 32; o > 0; o >>= 1) {
            ymx = fmaxf(ymx, __shfl_down(ymx, o));
            ymn = fminf(ymn, __shfl_down(ymn, o));
            xmx = fmaxf(xmx, __shfl_down(xmx, o));
            xmn = fminf(xmn, __shfl_down(xmn, o));
        }
        if (lane == 0) { rymx[wave] = ymx; rymn[wave] = ymn;
                         rxmx[wave] = xmx; rxmn[wave] = xmn; }
    }

    // stage 1: 6 matvecs {q,k,v} x {pw,pb} (384 threads)
    if (tid < 384) {
        const int mat = tid >> 6, d = tid & 63;
        const int rb = mat % 3, vecsel = mat / 3;
        const float* W = in_w + (rb * DD + d) * DD;
        const float* v = vecsel ? proj_b : proj_w;
        float s = 0.f;
        #pragma unroll
        for (int e = 0; e < DD; e += 4) {
            float4 wv = *(const float4*)(W + e);
            float4 vv = *(const float4*)(v + e);
            s += wv.x * vv.x + wv.y * vv.y + wv.z * vv.z + wv.w * vv.w;
        }
        if (vecsel) s += in_b[rb * DD + d];
        sv[mat][d] = s;
    }
    __syncthreads();

    // ---- phase B: stage 2 (u, e) + block min/max combine ----
    if (tid < 128) {
        const int which = tid >> 6, d = tid & 63;
        const float* W = out_w + d * DD;
        const float* v = sv[which ? 5 : 2];   // cv : av
        float s = 0.f;
        #pragma unroll
        for (int e = 0; e < DD; e += 4) {
            float4 wv = *(const float4*)(W + e);
            s += wv.x * v[e] + wv.y * v[e + 1] + wv.z * v[e + 2] + wv.w * v[e + 3];
        }
        if (which) cvec[2][d] = proj_b[d] + s + out_b[d];  // e (uncentered)
        else       cvec[1][d] = s;                          // u (uncentered)
    }
    if (tid == 511) {
        float a = rymx[0], m = rymn[0], xa = rxmx[0], xm = rxmn[0];
        #pragma unroll
        for (int i = 1; i < 8; ++i) {
            a  = fmaxf(a,  rymx[i]); m  = fminf(m,  rymn[i]);
            xa = fmaxf(xa, rxmx[i]); xm = fminf(xm, rxmn[i]);
        }
        bc[0] = a; bc[1] = m; bc[2] = xa; bc[3] = xm;
    }
    __syncthreads();

    // ---- phase C: scalars + Gram + centering (wave 0) ----
    if (wave == 0) {
        auto wred = [](float x) {
            #pragma unroll
            for (int o = 32; o > 0; o >>= 1) x += __shfl_down(x, o);
            return __shfl(x, 0);
        };
        const float aq = sv[0][lane], ak = sv[1][lane], cq = sv[3][lane];
        const float pw = proj_w[lane];
        const float u  = cvec[1][lane], e = cvec[2][lane];

        const float alpha = wred(aq * ak) * 0.125f;   // /sqrt(64)
        const float gamma = wred(cq * ak) * 0.125f;
        const float m_pw = wred(pw) * (1.f / DD);
        const float m_u  = wred(u)  * (1.f / DD);
        const float m_e  = wred(e)  * (1.f / DD);
        const float a  = pw - m_pw;
        const float bb = u  - m_u;
        const float c  = e  - m_e;
        const float G11 = wred(a * a)   * (1.f / DD);
        const float G22 = wred(bb * bb) * (1.f / DD);
        const float G33 = wred(c * c)   * (1.f / DD);
        const float G12 = wred(a * bb)  * (1.f / DD);
        const float G13 = wred(a * c)   * (1.f / DD);
        const float G23 = wred(bb * c)  * (1.f / DD);

        cvec[0][lane] = a; cvec[1][lane] = bb; cvec[2][lane] = c;
        if (lane == 0) {
            cst[0] = alpha; cst[1] = gamma;
            cst[2] = G11; cst[3] = G22; cst[4] = G33;
            cst[5] = G12; cst[6] = G13; cst[7] = G23;
        }
    }
    __syncthreads();

    const float ymax = bc[0], ymin = bc[1];
    const float alpha = cst[0], gamma = cst[1];
    // block c-range (affine image of [xmin,xmax], either orientation)
    const float cA = alpha * bc[3] + gamma, cB = alpha * bc[2] + gamma;
    const float c_lo = fminf(cA, cB), c_hi = fmaxf(cA, cB);
    const float mid = 0.5f * (c_lo + c_hi);
    const float hw  = fmaxf(0.5f * (c_hi - c_lo), 1e-6f);

    // ---- phase D: node evaluation — wave w handles nodes 2w, 2w+1 ----
    {
        const int j0 = 2 * wave, j1 = j0 + 1;
        const float cj0 = mid + hw * __cosf(PI_F * (j0 + 0.5f) * (1.f / NN));
        const float cj1 = mid + hw * __cosf(PI_F * (j1 + 0.5f) * (1.f / NN));
        const float c0l = cj0 * L2E, c1l = cj1 * L2E;
        const float s0  = fmaxf(c0l * ymax, c0l * ymin);   // shifts (log2 domain)
        const float s1  = fmaxf(c1l * ymax, c1l * ymin);
        float S00 = 0.f, S10 = 0.f, S01 = 0.f, S11 = 0.f;
        #pragma unroll
        for (int i = 0; i < 8; ++i) {
            const float yv = ys_l[lane + (i << 6)];
            const float e0 = fexp2(c0l * yv - s0);
            const float e1 = fexp2(c1l * yv - s1);
            S00 += e0; S10 += yv * e0;
            S01 += e1; S11 += yv * e1;
        }
        #pragma unroll
        for (int o = 32; o > 0; o >>= 1) {
            S00 += __shfl_down(S00, o); S10 += __shfl_down(S10, o);
            S01 += __shfl_down(S01, o); S11 += __shfl_down(S11, o);
        }
        if (lane == 0) { tj_l[j0] = S10 / S00; tj_l[j1] = S11 / S01; }
    }
    __syncthreads();

    // ---- phase E: DCT -> Chebyshev coefficients (wave 0, lane k<16) ----
    if (wave == 0 && lane < NN) {
        float acc = 0.f;
        #pragma unroll
        for (int j = 0; j < NN; ++j)
            acc += tj_l[j] * __cosf(PI_F * lane * (j + 0.5f) * (1.f / NN));
        float a = acc * (2.f / NN);
        if (lane == 0) a *= 0.5f;      // store a0/2 directly
        ac_l[lane] = a;
    }
    __syncthreads();

    // ---- phase F: per-query Clenshaw + closed-form LN stats ----
    float4 A0 = *(const float4*)&ac_l[0];
    float4 A1 = *(const float4*)&ac_l[4];
    float4 A2 = *(const float4*)&ac_l[8];
    float4 A3 = *(const float4*)&ac_l[12];
    const float a_[NN] = { A0.x, A0.y, A0.z, A0.w, A1.x, A1.y, A1.z, A1.w,
                           A2.x, A2.y, A2.z, A2.w, A3.x, A3.y, A3.z, A3.w };

    const float cq = alpha * xq + gamma;
    float xi = (cq - mid) / hw;
    xi = fminf(1.f, fmaxf(-1.f, xi));
    const float x2 = 2.f * xi;
    float b1 = 0.f, b2 = 0.f;
    #pragma unroll
    for (int k = NN - 1; k >= 1; --k) {
        const float bn = fmaf(x2, b1, a_[k] - b2);
        b2 = b1; b1 = bn;
    }
    const float t = fmaf(xi, b1, a_[0] - b2);   // a_[0] holds a0/2

    const float G11 = cst[2], G22 = cst[3], G33 = cst[4];
    const float G12 = cst[5], G13 = cst[6], G23 = cst[7];
    const float var = xq * xq * G11 + t * t * G22 + G33
                    + 2.f * (xq * t * G12 + xq * G13 + t * G23);
    const float inv = rsqrtf(var + LN_EPS);

    float pP = xq * inv, pT = t * inv, pI = inv;
    #pragma unroll
    for (int o = 32; o > 0; o >>= 1) {
        pP += __shfl_down(pP, o);
        pT += __shfl_down(pT, o);
        pI += __shfl_down(pI, o);
    }
    if (lane == 0) { rP[wave] = pP; rT[wave] = pT; rI[wave] = pI; }
    __syncthreads();
    if (tid == 0) {
        float sP = 0.f, sT = 0.f, sI = 0.f;
        #pragma unroll
        for (int i = 0; i < 8; ++i) { sP += rP[i]; sT += rT[i]; sI += rI[i]; }
        bc[4] = sP * (1.f / SS); bc[5] = sT * (1.f / SS); bc[6] = sI * (1.f / SS);
    }
    __syncthreads();

    if (tid < DD) {
        const float P = bc[4], T = bc[5], I = bc[6];
        float z = (P * cvec[0][tid] + T * cvec[1][tid] + I * cvec[2][tid]) * g[tid] + lb[tid];
        out[out_base + tid] = z;
    }
}

extern "C" void kernel_launch(void* const* d_in, const int* in_sizes, int n_in,
                              void* d_out, int out_size, void* d_ws, size_t ws_size,
                              hipStream_t stream) {
    const float* x_src    = (const float*)d_in[0];
    const float* x_tgt    = (const float*)d_in[1];
    const float* proj_w   = (const float*)d_in[2];
    const float* proj_b   = (const float*)d_in[3];
    const float* sa_in_w  = (const float*)d_in[4];
    const float* sa_in_b  = (const float*)d_in[5];
    const float* sa_out_w = (const float*)d_in[6];
    const float* sa_out_b = (const float*)d_in[7];
    const float* sa_ln_g  = (const float*)d_in[8];
    const float* sa_ln_b  = (const float*)d_in[9];
    const float* ca_in_w  = (const float*)d_in[10];
    const float* ca_in_b  = (const float*)d_in[11];
    const float* ca_out_w = (const float*)d_in[12];
    const float* ca_out_b = (const float*)d_in[13];
    const float* ca_ln_g  = (const float*)d_in[14];
    const float* ca_ln_b  = (const float*)d_in[15];
    float* out = (float*)d_out;

    fused_kernel<<<BB * 3, 512, 0, stream>>>(
        x_src, x_tgt, proj_w, proj_b,
        sa_in_w, sa_in_b, sa_out_w, sa_out_b, sa_ln_g, sa_ln_b,
        ca_in_w, ca_in_b, ca_out_w, ca_out_b, ca_ln_g, ca_ln_b,
        out);
}

// Round 6
// 99.306 us; speedup vs baseline: 1.2827x; 1.0643x over previous
//
#include <hip/hip_runtime.h>

#define BB 256
#define SS 512
#define DD 64
#define LN_EPS 1e-5f
#define L2E 1.4426950408889634f
#define NN 16            // Chebyshev nodes
#define PI_F 3.14159265358979f

// ws layout per type (floats), stride 256:
// [0]=alpha [1]=gamma [2..7]=G11,G22,G33,G12,G13,G23
// [8..71]=pw_centered [72..135]=u_centered [136..199]=e_centered
#define WS_TYPE_STRIDE 256

__device__ __forceinline__ float fexp2(float x) {
#if __has_builtin(__builtin_amdgcn_exp2f)
    return __builtin_amdgcn_exp2f(x);
#else
    float r; asm("v_exp_f32 %0, %1" : "=v"(r) : "v"(x)); return r;
#endif
}

// Algebra recap: h = x*pw + pb (rank-1+const) =>
//   attn[q,k] = softmax_k(c_q*y_k), c_q = alpha*x_q + gamma
//   r_q = x_q*pw + t_q*u + e, t_q = sum_k attn*y_k (scalar), t = f'(c)/f(c)
//   LN closed-form via 3x3 Gram of centered {pw,u,e}; seq-mean needs only
//   P=mean(x*inv), T=mean(t*inv), I=mean(inv).
// prep computes all weight-only constants ONCE (they are identical for every
// (b,task) of a type); main does per-block Chebyshev fit of t(c) (16 exact
// nodes) + Clenshaw + LN stats.

__global__ __launch_bounds__(1024) void prep_kernel(
    const float* __restrict__ proj_w, const float* __restrict__ proj_b,
    const float* __restrict__ sa_in_w, const float* __restrict__ sa_in_b,
    const float* __restrict__ sa_out_w, const float* __restrict__ sa_out_b,
    const float* __restrict__ ca_in_w, const float* __restrict__ ca_in_b,
    const float* __restrict__ ca_out_w, const float* __restrict__ ca_out_b,
    float* __restrict__ ws)
{
    const int tid = threadIdx.x;
    __shared__ float sv[2][6][DD];          // aq,ak,av,cq,ck,cv per type
    __shared__ float suu[2][DD], see[2][DD];

    // ---- stage 1: 12 matvecs, 768 parallel dots ----
    if (tid < 768) {
        const int mat = tid >> 6, d = tid & 63;
        const int type = mat / 6, which = mat % 6;
        const int rb = which % 3;            // q,k,v
        const int vecsel = which / 3;        // 0=pw, 1=pb
        const float* W = (type ? ca_in_w : sa_in_w) + (rb * DD + d) * DD;
        const float* v = vecsel ? proj_b : proj_w;
        float s = 0.f;
        #pragma unroll
        for (int e = 0; e < DD; e += 4) {
            float4 wv = *(const float4*)(W + e);
            float4 vv = *(const float4*)(v + e);
            s += wv.x * vv.x + wv.y * vv.y + wv.z * vv.z + wv.w * vv.w;
        }
        if (vecsel) s += (type ? ca_in_b : sa_in_b)[rb * DD + d];
        sv[type][which][d] = s;
    }
    __syncthreads();

    // ---- stage 2: u = Wo@av ; e = pb + Wo@cv + bo ----
    if (tid < 256) {
        const int mat = tid >> 6, d = tid & 63;
        const int type = mat >> 1, which = mat & 1;
        const float* W = (type ? ca_out_w : sa_out_w) + d * DD;
        const float* v = sv[type][which ? 5 : 2];     // cv : av
        float s = 0.f;
        #pragma unroll
        for (int e = 0; e < DD; e += 4) {
            float4 wv = *(const float4*)(W + e);
            s += wv.x * v[e] + wv.y * v[e + 1] + wv.z * v[e + 2] + wv.w * v[e + 3];
        }
        if (which) {
            s += (type ? ca_out_b : sa_out_b)[d];
            see[type][d] = proj_b[d] + s;
        } else {
            suu[type][d] = s;
        }
    }
    __syncthreads();

    // ---- stage 3: scalars + Gram + centering (wave w = type w) ----
    const int wave = tid >> 6, lane = tid & 63;
    if (wave < 2) {
        const int type = wave;
        auto wred = [](float x) {
            #pragma unroll
            for (int o = 32; o > 0; o >>= 1) x += __shfl_down(x, o);
            return __shfl(x, 0);
        };
        const float aq = sv[type][0][lane], ak = sv[type][1][lane];
        const float cq = sv[type][3][lane];
        const float pw = proj_w[lane];
        const float u  = suu[type][lane], e = see[type][lane];

        const float alpha = wred(aq * ak) * 0.125f;   // /sqrt(64)
        const float gamma = wred(cq * ak) * 0.125f;
        const float m_pw = wred(pw) * (1.f / DD);
        const float m_u  = wred(u)  * (1.f / DD);
        const float m_e  = wred(e)  * (1.f / DD);
        const float a  = pw - m_pw;
        const float bb = u  - m_u;
        const float c  = e  - m_e;
        const float G11 = wred(a * a)   * (1.f / DD);
        const float G22 = wred(bb * bb) * (1.f / DD);
        const float G33 = wred(c * c)   * (1.f / DD);
        const float G12 = wred(a * bb)  * (1.f / DD);
        const float G13 = wred(a * c)   * (1.f / DD);
        const float G23 = wred(bb * c)  * (1.f / DD);

        float* w = ws + type * WS_TYPE_STRIDE;
        w[8 + lane] = a; w[72 + lane] = bb; w[136 + lane] = c;
        if (lane == 0) {
            w[0] = alpha; w[1] = gamma;
            w[2] = G11; w[3] = G22; w[4] = G33; w[5] = G12; w[6] = G13; w[7] = G23;
        }
    }
}

__global__ __launch_bounds__(512) void main_kernel(
    const float* __restrict__ x_src, const float* __restrict__ x_tgt,
    const float* __restrict__ sa_ln_g, const float* __restrict__ sa_ln_b,
    const float* __restrict__ ca_ln_g, const float* __restrict__ ca_ln_b,
    const float* __restrict__ ws, float* __restrict__ out)
{
    const int tid  = threadIdx.x;
    const int b    = blockIdx.x / 3;
    const int task = blockIdx.x % 3;
    // task 0: sa_src (x=xs,y=xs) -> z_src_private @ B*D
    // task 1: sa_tgt (x=xt,y=xt) -> z_tgt_private @ 2*B*D
    // task 2: ca     (x=xs,y=xt) -> z_shared      @ 0
    const float* xq_g = (task == 1) ? (x_tgt + b * SS) : (x_src + b * SS);
    const float* y_g  = (task == 0) ? (x_src + b * SS) : (x_tgt + b * SS);
    const int type    = (task == 2) ? 1 : 0;
    const float* w  = ws + type * WS_TYPE_STRIDE;
    const float* g  = type ? ca_ln_g : sa_ln_g;
    const float* lb = type ? ca_ln_b : sa_ln_b;
    const int out_base = ((task == 0) ? BB * DD : (task == 1) ? 2 * BB * DD : 0) + b * DD;

    __shared__ __align__(16) float ys_l[SS];
    __shared__ float rymx[8], rymn[8], rxmx[8], rxmn[8];
    __shared__ float rP[8], rT[8], rI[8];
    __shared__ float tj_l[NN];
    __shared__ __align__(16) float ac_l[NN];
    __shared__ float bc[7];            // ymax,ymin,xmax,xmin,P,T,I

    const int wave = tid >> 6, lane = tid & 63;

    // ---- phase A: loads + per-wave min/max ----
    const float xq = xq_g[tid];
    const float y  = y_g[tid];
    ys_l[tid] = y;
    {
        float ymx = y, ymn = y, xmx = xq, xmn = xq;
        #pragma unroll
        for (int o = 32; o > 0; o >>= 1) {
            ymx = fmaxf(ymx, __shfl_down(ymx, o));
            ymn = fminf(ymn, __shfl_down(ymn, o));
            xmx = fmaxf(xmx, __shfl_down(xmx, o));
            xmn = fminf(xmn, __shfl_down(xmn, o));
        }
        if (lane == 0) { rymx[wave] = ymx; rymn[wave] = ymn;
                         rxmx[wave] = xmx; rxmn[wave] = xmn; }
    }
    __syncthreads();
    if (tid == 0) {
        float a = rymx[0], m = rymn[0], xa = rxmx[0], xm = rxmn[0];
        #pragma unroll
        for (int i = 1; i < 8; ++i) {
            a  = fmaxf(a,  rymx[i]); m  = fminf(m,  rymn[i]);
            xa = fmaxf(xa, rxmx[i]); xm = fminf(xm, rxmn[i]);
        }
        bc[0] = a; bc[1] = m; bc[2] = xa; bc[3] = xm;
    }
    __syncthreads();

    const float ymax = bc[0], ymin = bc[1];
    const float alpha = w[0], gamma = w[1];   // uniform -> scalar loads
    const float cA = alpha * bc[3] + gamma, cB = alpha * bc[2] + gamma;
    const float c_lo = fminf(cA, cB), c_hi = fmaxf(cA, cB);
    const float mid = 0.5f * (c_lo + c_hi);
    const float hw  = fmaxf(0.5f * (c_hi - c_lo), 1e-6f);

    // ---- phase D: exact t at 16 Chebyshev nodes (wave w -> nodes 2w,2w+1) ----
    {
        const int j0 = 2 * wave, j1 = j0 + 1;
        const float cj0 = mid + hw * __cosf(PI_F * (j0 + 0.5f) * (1.f / NN));
        const float cj1 = mid + hw * __cosf(PI_F * (j1 + 0.5f) * (1.f / NN));
        const float c0l = cj0 * L2E, c1l = cj1 * L2E;
        const float s0  = fmaxf(c0l * ymax, c0l * ymin);
        const float s1  = fmaxf(c1l * ymax, c1l * ymin);
        float S00 = 0.f, S10 = 0.f, S01 = 0.f, S11 = 0.f;
        #pragma unroll
        for (int i = 0; i < 8; ++i) {
            const float yv = ys_l[lane + (i << 6)];
            const float e0 = fexp2(c0l * yv - s0);
            const float e1 = fexp2(c1l * yv - s1);
            S00 += e0; S10 += yv * e0;
            S01 += e1; S11 += yv * e1;
        }
        #pragma unroll
        for (int o = 32; o > 0; o >>= 1) {
            S00 += __shfl_down(S00, o); S10 += __shfl_down(S10, o);
            S01 += __shfl_down(S01, o); S11 += __shfl_down(S11, o);
        }
        if (lane == 0) { tj_l[j0] = S10 / S00; tj_l[j1] = S11 / S01; }
    }
    __syncthreads();

    // ---- phase E: DCT -> Chebyshev coefficients ----
    if (wave == 0 && lane < NN) {
        float acc = 0.f;
        #pragma unroll
        for (int j = 0; j < NN; ++j)
            acc += tj_l[j] * __cosf(PI_F * lane * (j + 0.5f) * (1.f / NN));
        float a = acc * (2.f / NN);
        if (lane == 0) a *= 0.5f;      // store a0/2
        ac_l[lane] = a;
    }
    __syncthreads();

    // ---- phase F: per-query Clenshaw + closed-form LN stats ----
    float4 A0 = *(const float4*)&ac_l[0];
    float4 A1 = *(const float4*)&ac_l[4];
    float4 A2 = *(const float4*)&ac_l[8];
    float4 A3 = *(const float4*)&ac_l[12];
    const float a_[NN] = { A0.x, A0.y, A0.z, A0.w, A1.x, A1.y, A1.z, A1.w,
                           A2.x, A2.y, A2.z, A2.w, A3.x, A3.y, A3.z, A3.w };

    const float cq = alpha * xq + gamma;
    float xi = (cq - mid) / hw;
    xi = fminf(1.f, fmaxf(-1.f, xi));
    const float x2 = 2.f * xi;
    float b1 = 0.f, b2 = 0.f;
    #pragma unroll
    for (int k = NN - 1; k >= 1; --k) {
        const float bn = fmaf(x2, b1, a_[k] - b2);
        b2 = b1; b1 = bn;
    }
    const float t = fmaf(xi, b1, a_[0] - b2);   // a_[0] = a0/2

    const float G11 = w[2], G22 = w[3], G33 = w[4];
    const float G12 = w[5], G13 = w[6], G23 = w[7];
    const float var = xq * xq * G11 + t * t * G22 + G33
                    + 2.f * (xq * t * G12 + xq * G13 + t * G23);
    const float inv = rsqrtf(var + LN_EPS);

    float pP = xq * inv, pT = t * inv, pI = inv;
    #pragma unroll
    for (int o = 32; o > 0; o >>= 1) {
        pP += __shfl_down(pP, o);
        pT += __shfl_down(pT, o);
        pI += __shfl_down(pI, o);
    }
    if (lane == 0) { rP[wave] = pP; rT[wave] = pT; rI[wave] = pI; }
    __syncthreads();
    if (tid == 0) {
        float sP = 0.f, sT = 0.f, sI = 0.f;
        #pragma unroll
        for (int i = 0; i < 8; ++i) { sP += rP[i]; sT += rT[i]; sI += rI[i]; }
        bc[4] = sP * (1.f / SS); bc[5] = sT * (1.f / SS); bc[6] = sI * (1.f / SS);
    }
    __syncthreads();

    if (tid < DD) {
        const float P = bc[4], T = bc[5], I = bc[6];
        float z = (P * w[8 + tid] + T * w[72 + tid] + I * w[136 + tid]) * g[tid] + lb[tid];
        out[out_base + tid] = z;
    }
}

extern "C" void kernel_launch(void* const* d_in, const int* in_sizes, int n_in,
                              void* d_out, int out_size, void* d_ws, size_t ws_size,
                              hipStream_t stream) {
    const float* x_src    = (const float*)d_in[0];
    const float* x_tgt    = (const float*)d_in[1];
    const float* proj_w   = (const float*)d_in[2];
    const float* proj_b   = (const float*)d_in[3];
    const float* sa_in_w  = (const float*)d_in[4];
    const float* sa_in_b  = (const float*)d_in[5];
    const float* sa_out_w = (const float*)d_in[6];
    const float* sa_out_b = (const float*)d_in[7];
    const float* sa_ln_g  = (const float*)d_in[8];
    const float* sa_ln_b  = (const float*)d_in[9];
    const float* ca_in_w  = (const float*)d_in[10];
    const float* ca_in_b  = (const float*)d_in[11];
    const float* ca_out_w = (const float*)d_in[12];
    const float* ca_out_b = (const float*)d_in[13];
    const float* ca_ln_g  = (const float*)d_in[14];
    const float* ca_ln_b  = (const float*)d_in[15];
    float* ws  = (float*)d_ws;
    float* out = (float*)d_out;

    prep_kernel<<<1, 1024, 0, stream>>>(proj_w, proj_b,
                                        sa_in_w, sa_in_b, sa_out_w, sa_out_b,
                                        ca_in_w, ca_in_b, ca_out_w, ca_out_b, ws);
    main_kernel<<<BB * 3, 512, 0, stream>>>(x_src, x_tgt,
                                            sa_ln_g, sa_ln_b, ca_ln_g, ca_ln_b,
                                            ws, out);
}